// Round 1
// baseline (1639.753 us; speedup 1.0000x reference)
//
#include <hip/hip_runtime.h>
#include <stdint.h>

#define NQ 8192
#define NS 16384
#define DIM 512
#define NC 64

#define BM 128
#define BN 128
#define BK 16
#define NSPLIT 32
#define SCHUNK (NS / NSPLIT)   // 512 supports per block
#define NTILES (SCHUNK / BN)   // 4 BN-tiles per block

// Order-preserving monotone map f32 -> u32 (larger float -> larger key)
__device__ __forceinline__ uint32_t fkey(float f) {
  uint32_t u = __float_as_uint(f);
  return (u & 0x80000000u) ? ~u : (u | 0x80000000u);
}

// One wave per row: rsqrt(max(sum(x^2), eps))
__global__ void rnorm_kernel(const float* __restrict__ X, float* __restrict__ r, int nrows) {
  int wave = threadIdx.x >> 6;
  int lane = threadIdx.x & 63;
  int row = blockIdx.x * 4 + wave;
  if (row >= nrows) return;
  const float4* x = (const float4*)(X + (size_t)row * DIM);
  float4 v0 = x[lane];
  float4 v1 = x[lane + 64];
  float s = v0.x*v0.x + v0.y*v0.y + v0.z*v0.z + v0.w*v0.w
          + v1.x*v1.x + v1.y*v1.y + v1.z*v1.z + v1.w*v1.w;
  #pragma unroll
  for (int off = 32; off; off >>= 1) s += __shfl_xor(s, off);
  if (lane == 0) r[row] = rsqrtf(fmaxf(s, 1e-12f));
}

// labels from one-hot + init packed results (must re-init every call)
__global__ void label_init_kernel(const float* __restrict__ oh, int* __restrict__ lab,
                                  unsigned long long* __restrict__ packed) {
  int i = blockIdx.x * 256 + threadIdx.x;
  if (i < NQ) packed[i] = 0ull;   // key 0 == -NaN, loses to everything real
  if (i < NS) {
    const float* row = oh + (size_t)i * NC;
    int l = 0;
    #pragma unroll
    for (int j = 0; j < NC; ++j) l = (row[j] > 0.5f) ? j : l;
    lab[i] = l;
  }
}

__global__ __launch_bounds__(256, 2) void knn_kernel(
    const float* __restrict__ Q, const float* __restrict__ S,
    const float* __restrict__ rq, const float* __restrict__ rs,
    unsigned long long* __restrict__ packed)
{
  // k-major (transposed) tiles: fragment reads are aligned float4
  __shared__ __align__(16) float As[BK][BM + 4];
  __shared__ __align__(16) float Bs[BK][BN + 4];

  const int tid = threadIdx.x;
  const int tx = tid & 15;   // support dim, 4 cols + 4 cols (+64)
  const int ty = tid >> 4;   // query dim,  4 rows + 4 rows (+64)
  const int qbase = blockIdx.x * BM;
  const int sbase = blockIdx.y * SCHUNK;

  float bestv[8];
  int   bestn[8];
  #pragma unroll
  for (int i = 0; i < 8; ++i) { bestv[i] = -2.0f; bestn[i] = 0; }

  for (int t = 0; t < NTILES; ++t) {
    const int sb = sbase + t * BN;
    float acc[8][8];
    #pragma unroll
    for (int i = 0; i < 8; ++i)
      #pragma unroll
      for (int j = 0; j < 8; ++j) acc[i][j] = 0.f;

    for (int kt = 0; kt < DIM; kt += BK) {
      // stage: 128 rows x 16 k each for A and B; scales folded in
      #pragma unroll
      for (int u = 0; u < 2; ++u) {
        int f = tid + u * 256;       // 0..511 float4 slots
        int row = f >> 2;            // 0..127
        int kv = f & 3;              // which float4 along k
        float4 a = *(const float4*)(Q + (size_t)(qbase + row) * DIM + kt + kv * 4);
        float sca = rq[qbase + row];
        As[kv*4+0][row] = a.x * sca;
        As[kv*4+1][row] = a.y * sca;
        As[kv*4+2][row] = a.z * sca;
        As[kv*4+3][row] = a.w * sca;
        float4 b = *(const float4*)(S + (size_t)(sb + row) * DIM + kt + kv * 4);
        float scb = rs[sb + row];
        Bs[kv*4+0][row] = b.x * scb;
        Bs[kv*4+1][row] = b.y * scb;
        Bs[kv*4+2][row] = b.z * scb;
        Bs[kv*4+3][row] = b.w * scb;
      }
      __syncthreads();
      #pragma unroll
      for (int k = 0; k < BK; ++k) {
        float4 a0 = *(const float4*)&As[k][4*ty];
        float4 a1 = *(const float4*)&As[k][64 + 4*ty];
        float4 b0 = *(const float4*)&Bs[k][4*tx];
        float4 b1 = *(const float4*)&Bs[k][64 + 4*tx];
        float av[8] = {a0.x,a0.y,a0.z,a0.w,a1.x,a1.y,a1.z,a1.w};
        float bv[8] = {b0.x,b0.y,b0.z,b0.w,b1.x,b1.y,b1.z,b1.w};
        #pragma unroll
        for (int i = 0; i < 8; ++i)
          #pragma unroll
          for (int j = 0; j < 8; ++j)
            acc[i][j] = fmaf(av[i], bv[j], acc[i][j]);
      }
      __syncthreads();
    }

    // reduce max over this tile's 128 columns; min-index tie-break
    #pragma unroll
    for (int i = 0; i < 8; ++i) {
      float v = acc[i][0];
      int   n = sb + 4*tx;
      #pragma unroll
      for (int j = 1; j < 8; ++j) {
        int nj = sb + ((j < 4) ? (4*tx + j) : (64 + 4*tx + (j - 4)));
        float vj = acc[i][j];
        if (vj > v) { v = vj; n = nj; }   // strict >: keeps lowest index
      }
      // reduce across the 16 tx lanes (contiguous lane group within wave)
      #pragma unroll
      for (int off = 1; off < 16; off <<= 1) {
        float ov = __shfl_xor(v, off);
        int   on = __shfl_xor(n, off);
        if (ov > v || (ov == v && on < n)) { v = ov; n = on; }
      }
      if (v > bestv[i] || (v == bestv[i] && n < bestn[i])) { bestv[i] = v; bestn[i] = n; }
    }
  }

  if (tx == 0) {
    #pragma unroll
    for (int i = 0; i < 8; ++i) {
      int row = qbase + ((i < 4) ? (4*ty + i) : (64 + 4*ty + (i - 4)));
      unsigned long long p =
          ((unsigned long long)fkey(bestv[i]) << 32) | (uint32_t)(~(uint32_t)bestn[i]);
      atomicMax(&packed[row], p);
    }
  }
}

__global__ void finalize_kernel(const unsigned long long* __restrict__ packed,
                                const int* __restrict__ lab, float* __restrict__ out) {
  int gid = blockIdx.x * 256 + threadIdx.x;
  if (gid >= NQ * NC) return;
  int q = gid >> 6;
  int c = gid & 63;
  unsigned long long p = packed[q];
  uint32_t n = ~(uint32_t)p;                 // support index (ties -> lowest)
  uint32_t key = (uint32_t)(p >> 32);
  uint32_t u = (key & 0x80000000u) ? (key & 0x7FFFFFFFu) : ~key;
  float v = __uint_as_float(u);
  out[gid] = (c == lab[n]) ? v : 0.0f;
}

extern "C" void kernel_launch(void* const* d_in, const int* in_sizes, int n_in,
                              void* d_out, int out_size, void* d_ws, size_t ws_size,
                              hipStream_t stream) {
  const float* Q  = (const float*)d_in[0];   // [8192, 512]
  const float* S  = (const float*)d_in[1];   // [16384, 512]
  const float* OH = (const float*)d_in[2];   // [16384, 64]
  float* out = (float*)d_out;                // [8192, 64]

  char* ws = (char*)d_ws;
  float* rq = (float*)ws;                                   //  32 KB
  float* rs = (float*)(ws + 32768);                         //  64 KB
  int*   lab = (int*)(ws + 98304);                          //  64 KB
  unsigned long long* packed = (unsigned long long*)(ws + 163840); // 64 KB

  rnorm_kernel<<<NQ / 4, 256, 0, stream>>>(Q, rq, NQ);
  rnorm_kernel<<<NS / 4, 256, 0, stream>>>(S, rs, NS);
  label_init_kernel<<<NS / 256, 256, 0, stream>>>(OH, lab, packed);

  dim3 grid(NQ / BM, NSPLIT);   // 64 x 32
  knn_kernel<<<grid, 256, 0, stream>>>(Q, S, rq, rs, packed);

  finalize_kernel<<<(NQ * NC) / 256, 256, 0, stream>>>(packed, lab, out);
}

// Round 2
// 467.521 us; speedup vs baseline: 3.5073x; 3.5073x over previous
//
#include <hip/hip_runtime.h>
#include <stdint.h>

#define NQ 8192
#define NS 16384
#define DIM 512
#define NC 64
#define NSPLIT 32
#define SCHUNK (NS / NSPLIT)   // 512 supports per block-row of the split

typedef unsigned short ushort;
typedef __attribute__((ext_vector_type(8))) short bf16x8;
typedef __attribute__((ext_vector_type(4))) float f32x4;

// ---------- helpers ----------

// Order-preserving monotone map f32 -> u32 (larger float -> larger key)
__device__ __forceinline__ uint32_t fkey(float f) {
  uint32_t u = __float_as_uint(f);
  return (u & 0x80000000u) ? ~u : (u | 0x80000000u);
}

__device__ __forceinline__ ushort f2bf_rne(float f) {
  uint32_t u = __float_as_uint(f);
  uint32_t r = (u + 0x7fffu + ((u >> 16) & 1u)) >> 16;
  return (ushort)r;
}
__device__ __forceinline__ float bf2f(ushort h) {
  return __uint_as_float(((uint32_t)h) << 16);
}

__device__ __forceinline__ void gload_lds16(const void* g, void* lds) {
  __builtin_amdgcn_global_load_lds(
      (const __attribute__((address_space(1))) uint32_t*)g,
      (__attribute__((address_space(3))) uint32_t*)lds, 16, 0, 0);
}

// ---------- pre-pass: row-normalize + bf16 hi/lo split (one wave per row) ----------
__global__ void norm_split_kernel(const float* __restrict__ X,
                                  ushort* __restrict__ Xhi, ushort* __restrict__ Xlo,
                                  int nrows) {
  int w = threadIdx.x >> 6;
  int l = threadIdx.x & 63;
  int row = blockIdx.x * 4 + w;
  if (row >= nrows) return;
  const float4* x = (const float4*)(X + (size_t)row * DIM);
  float4 v0 = x[l];
  float4 v1 = x[l + 64];
  float s = v0.x*v0.x + v0.y*v0.y + v0.z*v0.z + v0.w*v0.w
          + v1.x*v1.x + v1.y*v1.y + v1.z*v1.z + v1.w*v1.w;
  #pragma unroll
  for (int off = 32; off; off >>= 1) s += __shfl_xor(s, off);
  float r = rsqrtf(fmaxf(s, 1e-12f));
  float a[8] = {v0.x*r, v0.y*r, v0.z*r, v0.w*r, v1.x*r, v1.y*r, v1.z*r, v1.w*r};
  ushort hi[8], lo[8];
  #pragma unroll
  for (int e = 0; e < 8; ++e) {
    hi[e] = f2bf_rne(a[e]);
    lo[e] = f2bf_rne(a[e] - bf2f(hi[e]));
  }
  size_t base = (size_t)row * DIM + 4 * l;
  *(ushort4*)&Xhi[base]       = make_ushort4(hi[0], hi[1], hi[2], hi[3]);
  *(ushort4*)&Xhi[base + 256] = make_ushort4(hi[4], hi[5], hi[6], hi[7]);
  *(ushort4*)&Xlo[base]       = make_ushort4(lo[0], lo[1], lo[2], lo[3]);
  *(ushort4*)&Xlo[base + 256] = make_ushort4(lo[4], lo[5], lo[6], lo[7]);
}

// labels from one-hot + init packed results (must re-init every call)
__global__ void label_init_kernel(const float* __restrict__ oh, int* __restrict__ lab,
                                  unsigned long long* __restrict__ packed) {
  int i = blockIdx.x * 256 + threadIdx.x;
  if (i < NQ) packed[i] = 0ull;   // key 0 loses to any real similarity
  if (i < NS) {
    const float* row = oh + (size_t)i * NC;
    int l = 0;
    #pragma unroll
    for (int j = 0; j < NC; ++j) l = (row[j] > 0.5f) ? j : l;
    lab[i] = l;
  }
}

// ---------- main: bf16x3 MFMA cosine-sim + fused row-argmax ----------
__global__ __launch_bounds__(256, 2) void knn_mfma_kernel(
    const ushort* __restrict__ Qhi, const ushort* __restrict__ Qlo,
    const ushort* __restrict__ Shi, const ushort* __restrict__ Slo,
    unsigned long long* __restrict__ packed)
{
  // linear [row][32] bf16 tiles, 64B row stride (uniform bank-group spread)
  __shared__ ushort Ahi[128 * 32], Alo[128 * 32], Bhi[128 * 32], Blo[128 * 32];

  const int tid = threadIdx.x;
  const int w  = tid >> 6, l = tid & 63;
  const int wr = w >> 1, wc = w & 1;          // wave -> 64x64 quadrant
  const int c  = l & 15, g = l >> 4;          // frag col / k-group
  const int qbase = blockIdx.x * 128;
  const int sbase = blockIdx.y * SCHUNK;

  // staging geometry: per issue 256 threads cover 64 rows x 64B
  const int srow = w * 16 + (l >> 2);         // row within 64-row chunk
  const int scol = (l & 3) * 8;               // bf16 col within row
  const int ldso = w * 16 * 32;               // wave-uniform LDS base (ushort idx)

  float bestv[16];
  int   bestn[16];
  #pragma unroll
  for (int i = 0; i < 16; ++i) { bestv[i] = -2.0f; bestn[i] = 0; }

  for (int t = 0; t < SCHUNK / 128; ++t) {
    const int sb = sbase + t * 128;
    f32x4 acc[4][4];
    #pragma unroll
    for (int i = 0; i < 4; ++i)
      #pragma unroll
      for (int j = 0; j < 4; ++j) acc[i][j] = (f32x4)0.0f;

    for (int kt = 0; kt < DIM; kt += 32) {
      __syncthreads();   // protect LDS from previous compute
      #pragma unroll
      for (int u = 0; u < 2; ++u) {
        size_t ga = (size_t)(qbase + u * 64 + srow) * DIM + kt + scol;
        size_t gb = (size_t)(sb    + u * 64 + srow) * DIM + kt + scol;
        int lo_ = ldso + u * 64 * 32;
        gload_lds16(Qhi + ga, &Ahi[lo_]);
        gload_lds16(Qlo + ga, &Alo[lo_]);
        gload_lds16(Shi + gb, &Bhi[lo_]);
        gload_lds16(Slo + gb, &Blo[lo_]);
      }
      __syncthreads();   // compiler drains vmcnt before barrier

      bf16x8 ah[4], al[4], bh[4], bl[4];
      #pragma unroll
      for (int i = 0; i < 4; ++i) {
        int ro = (wr * 64 + i * 16 + c) * 32 + g * 8;
        ah[i] = *(const bf16x8*)&Ahi[ro];
        al[i] = *(const bf16x8*)&Alo[ro];
      }
      #pragma unroll
      for (int j = 0; j < 4; ++j) {
        int ro = (wc * 64 + j * 16 + c) * 32 + g * 8;
        bh[j] = *(const bf16x8*)&Bhi[ro];
        bl[j] = *(const bf16x8*)&Blo[ro];
      }
      #pragma unroll
      for (int i = 0; i < 4; ++i)
        #pragma unroll
        for (int j = 0; j < 4; ++j) {
          acc[i][j] = __builtin_amdgcn_mfma_f32_16x16x32_bf16(ah[i], bh[j], acc[i][j], 0, 0, 0);
          acc[i][j] = __builtin_amdgcn_mfma_f32_16x16x32_bf16(ah[i], bl[j], acc[i][j], 0, 0, 0);
          acc[i][j] = __builtin_amdgcn_mfma_f32_16x16x32_bf16(al[i], bh[j], acc[i][j], 0, 0, 0);
        }
    }

    // fused argmax: C/D layout col=lane&15, row=(lane>>4)*4+reg  [m89-verified]
    #pragma unroll
    for (int i = 0; i < 4; ++i)
      #pragma unroll
      for (int r = 0; r < 4; ++r) {
        float v = acc[i][0][r];
        int   n = sb + wc * 64 + c;
        #pragma unroll
        for (int j = 1; j < 4; ++j) {
          float vj = acc[i][j][r];
          int   nj = sb + wc * 64 + j * 16 + c;
          if (vj > v) { v = vj; n = nj; }     // strict >: n ascends with j
        }
        #pragma unroll
        for (int off = 1; off < 16; off <<= 1) {
          float ov = __shfl_xor(v, off);
          int   on = __shfl_xor(n, off);
          if (ov > v || (ov == v && on < n)) { v = ov; n = on; }
        }
        int bi = i * 4 + r;
        if (v > bestv[bi] || (v == bestv[bi] && n < bestn[bi])) { bestv[bi] = v; bestn[bi] = n; }
      }
  }

  if (c == 0) {
    #pragma unroll
    for (int i = 0; i < 4; ++i)
      #pragma unroll
      for (int r = 0; r < 4; ++r) {
        int row = qbase + wr * 64 + i * 16 + g * 4 + r;
        unsigned long long p =
            ((unsigned long long)fkey(bestv[i * 4 + r]) << 32) |
            (uint32_t)(~(uint32_t)bestn[i * 4 + r]);
        atomicMax(&packed[row], p);
      }
  }
}

__global__ void finalize_kernel(const unsigned long long* __restrict__ packed,
                                const int* __restrict__ lab, float* __restrict__ out) {
  int gid = blockIdx.x * 256 + threadIdx.x;
  if (gid >= NQ * NC) return;
  int q = gid >> 6;
  int cl = gid & 63;
  unsigned long long p = packed[q];
  uint32_t n = ~(uint32_t)p;
  uint32_t key = (uint32_t)(p >> 32);
  uint32_t u = (key & 0x80000000u) ? (key & 0x7FFFFFFFu) : ~key;
  float v = __uint_as_float(u);
  out[gid] = (cl == lab[n]) ? v : 0.0f;
}

// ---------- fp32 fallback path (used only if workspace is too small) ----------
__global__ void rnorm_kernel(const float* __restrict__ X, float* __restrict__ r, int nrows) {
  int wave = threadIdx.x >> 6;
  int lane = threadIdx.x & 63;
  int row = blockIdx.x * 4 + wave;
  if (row >= nrows) return;
  const float4* x = (const float4*)(X + (size_t)row * DIM);
  float4 v0 = x[lane];
  float4 v1 = x[lane + 64];
  float s = v0.x*v0.x + v0.y*v0.y + v0.z*v0.z + v0.w*v0.w
          + v1.x*v1.x + v1.y*v1.y + v1.z*v1.z + v1.w*v1.w;
  #pragma unroll
  for (int off = 32; off; off >>= 1) s += __shfl_xor(s, off);
  if (lane == 0) r[row] = rsqrtf(fmaxf(s, 1e-12f));
}

__global__ __launch_bounds__(256, 2) void knn_f32_kernel(
    const float* __restrict__ Q, const float* __restrict__ S,
    const float* __restrict__ rq, const float* __restrict__ rs,
    unsigned long long* __restrict__ packed)
{
  __shared__ __align__(16) float As[16][128 + 4];
  __shared__ __align__(16) float Bs[16][128 + 4];
  const int tid = threadIdx.x;
  const int tx = tid & 15;
  const int ty = tid >> 4;
  const int qbase = blockIdx.x * 128;
  const int sbase = blockIdx.y * SCHUNK;
  float bestv[8]; int bestn[8];
  #pragma unroll
  for (int i = 0; i < 8; ++i) { bestv[i] = -2.0f; bestn[i] = 0; }
  for (int t = 0; t < SCHUNK / 128; ++t) {
    const int sb = sbase + t * 128;
    float acc[8][8];
    #pragma unroll
    for (int i = 0; i < 8; ++i)
      #pragma unroll
      for (int j = 0; j < 8; ++j) acc[i][j] = 0.f;
    for (int kt = 0; kt < DIM; kt += 16) {
      #pragma unroll
      for (int u = 0; u < 2; ++u) {
        int f = tid + u * 256;
        int row = f >> 2;
        int kv = f & 3;
        float4 a = *(const float4*)(Q + (size_t)(qbase + row) * DIM + kt + kv * 4);
        float sca = rq[qbase + row];
        As[kv*4+0][row] = a.x * sca; As[kv*4+1][row] = a.y * sca;
        As[kv*4+2][row] = a.z * sca; As[kv*4+3][row] = a.w * sca;
        float4 b = *(const float4*)(S + (size_t)(sb + row) * DIM + kt + kv * 4);
        float scb = rs[sb + row];
        Bs[kv*4+0][row] = b.x * scb; Bs[kv*4+1][row] = b.y * scb;
        Bs[kv*4+2][row] = b.z * scb; Bs[kv*4+3][row] = b.w * scb;
      }
      __syncthreads();
      #pragma unroll
      for (int k = 0; k < 16; ++k) {
        float4 a0 = *(const float4*)&As[k][4*ty];
        float4 a1 = *(const float4*)&As[k][64 + 4*ty];
        float4 b0 = *(const float4*)&Bs[k][4*tx];
        float4 b1 = *(const float4*)&Bs[k][64 + 4*tx];
        float av[8] = {a0.x,a0.y,a0.z,a0.w,a1.x,a1.y,a1.z,a1.w};
        float bv[8] = {b0.x,b0.y,b0.z,b0.w,b1.x,b1.y,b1.z,b1.w};
        #pragma unroll
        for (int i = 0; i < 8; ++i)
          #pragma unroll
          for (int j = 0; j < 8; ++j)
            acc[i][j] = fmaf(av[i], bv[j], acc[i][j]);
      }
      __syncthreads();
    }
    #pragma unroll
    for (int i = 0; i < 8; ++i) {
      float v = acc[i][0];
      int   n = sb + 4*tx;
      #pragma unroll
      for (int j = 1; j < 8; ++j) {
        int nj = sb + ((j < 4) ? (4*tx + j) : (64 + 4*tx + (j - 4)));
        float vj = acc[i][j];
        if (vj > v) { v = vj; n = nj; }
      }
      #pragma unroll
      for (int off = 1; off < 16; off <<= 1) {
        float ov = __shfl_xor(v, off);
        int   on = __shfl_xor(n, off);
        if (ov > v || (ov == v && on < n)) { v = ov; n = on; }
      }
      if (v > bestv[i] || (v == bestv[i] && n < bestn[i])) { bestv[i] = v; bestn[i] = n; }
    }
  }
  if (tx == 0) {
    #pragma unroll
    for (int i = 0; i < 8; ++i) {
      int row = qbase + ((i < 4) ? (4*ty + i) : (64 + 4*ty + (i - 4)));
      unsigned long long p =
          ((unsigned long long)fkey(bestv[i]) << 32) | (uint32_t)(~(uint32_t)bestn[i]);
      atomicMax(&packed[row], p);
    }
  }
}

// ---------- launch ----------
extern "C" void kernel_launch(void* const* d_in, const int* in_sizes, int n_in,
                              void* d_out, int out_size, void* d_ws, size_t ws_size,
                              hipStream_t stream) {
  const float* Q  = (const float*)d_in[0];   // [8192, 512]
  const float* S  = (const float*)d_in[1];   // [16384, 512]
  const float* OH = (const float*)d_in[2];   // [16384, 64]
  float* out = (float*)d_out;                // [8192, 64]

  char* ws = (char*)d_ws;
  int* lab = (int*)ws;                                              // 64 KB @ 0
  unsigned long long* packed = (unsigned long long*)(ws + 65536);   // 64 KB

  const size_t QHI = 131072;
  const size_t QLO = QHI + (size_t)NQ * DIM * 2;        // +8 MB
  const size_t SHI = QLO + (size_t)NQ * DIM * 2;        // +8 MB
  const size_t SLO = SHI + (size_t)NS * DIM * 2;        // +16 MB
  const size_t NEED = SLO + (size_t)NS * DIM * 2;       // ~48.1 MB total

  if (ws_size >= NEED) {
    ushort* Qhi = (ushort*)(ws + QHI);
    ushort* Qlo = (ushort*)(ws + QLO);
    ushort* Shi = (ushort*)(ws + SHI);
    ushort* Slo = (ushort*)(ws + SLO);

    norm_split_kernel<<<NQ / 4, 256, 0, stream>>>(Q, Qhi, Qlo, NQ);
    norm_split_kernel<<<NS / 4, 256, 0, stream>>>(S, Shi, Slo, NS);
    label_init_kernel<<<NS / 256, 256, 0, stream>>>(OH, lab, packed);

    dim3 grid(NQ / 128, NSPLIT);   // 64 x 32
    knn_mfma_kernel<<<grid, 256, 0, stream>>>(Qhi, Qlo, Shi, Slo, packed);
  } else {
    float* rq = (float*)(ws + 131072);                  // 32 KB
    float* rs = (float*)(ws + 131072 + 32768);          // 64 KB
    rnorm_kernel<<<NQ / 4, 256, 0, stream>>>(Q, rq, NQ);
    rnorm_kernel<<<NS / 4, 256, 0, stream>>>(S, rs, NS);
    label_init_kernel<<<NS / 256, 256, 0, stream>>>(OH, lab, packed);
    dim3 grid(NQ / 128, NSPLIT);
    knn_f32_kernel<<<grid, 256, 0, stream>>>(Q, S, rq, rs, packed);
  }

  finalize_kernel<<<(NQ * NC) / 256, 256, 0, stream>>>(packed, lab, out);
}

// Round 3
// 431.766 us; speedup vs baseline: 3.7978x; 1.0828x over previous
//
#include <hip/hip_runtime.h>
#include <stdint.h>

#define NQ 8192
#define NS 16384
#define DIM 512
#define NC 64

#define BM 256
#define BN 256
#define BK 32
#define SSPLIT 16
#define SCHUNK (NS / SSPLIT)      // 1024 supports per block
#define NTILES (SCHUNK / BN)      // 4
#define KSTEPS (DIM / BK)         // 16
#define TOTKS (NTILES * KSTEPS)   // 64 linear K-steps per block

typedef unsigned short ushort;
typedef __attribute__((ext_vector_type(8))) short bf16x8;
typedef __attribute__((ext_vector_type(4))) float f32x4;

// ---------- helpers ----------
__device__ __forceinline__ uint32_t fkey(float f) {
  uint32_t u = __float_as_uint(f);
  return (u & 0x80000000u) ? ~u : (u | 0x80000000u);
}
__device__ __forceinline__ ushort f2bf_rne(float f) {
  uint32_t u = __float_as_uint(f);
  uint32_t r = (u + 0x7fffu + ((u >> 16) & 1u)) >> 16;
  return (ushort)r;
}
__device__ __forceinline__ float bf2f(ushort h) {
  return __uint_as_float(((uint32_t)h) << 16);
}
__device__ __forceinline__ void gload_lds16(const void* g, void* lds) {
  __builtin_amdgcn_global_load_lds(
      (const __attribute__((address_space(1))) uint32_t*)g,
      (__attribute__((address_space(3))) uint32_t*)lds, 16, 0, 0);
}

// ---------- pre-pass: row-normalize + bf16 hi/lo split ----------
__global__ void norm_split_kernel(const float* __restrict__ X,
                                  ushort* __restrict__ Xhi, ushort* __restrict__ Xlo,
                                  int nrows) {
  int w = threadIdx.x >> 6;
  int l = threadIdx.x & 63;
  int row = blockIdx.x * 4 + w;
  if (row >= nrows) return;
  const float4* x = (const float4*)(X + (size_t)row * DIM);
  float4 v0 = x[l];
  float4 v1 = x[l + 64];
  float s = v0.x*v0.x + v0.y*v0.y + v0.z*v0.z + v0.w*v0.w
          + v1.x*v1.x + v1.y*v1.y + v1.z*v1.z + v1.w*v1.w;
  #pragma unroll
  for (int off = 32; off; off >>= 1) s += __shfl_xor(s, off);
  float r = rsqrtf(fmaxf(s, 1e-12f));
  float a[8] = {v0.x*r, v0.y*r, v0.z*r, v0.w*r, v1.x*r, v1.y*r, v1.z*r, v1.w*r};
  ushort hi[8], lo[8];
  #pragma unroll
  for (int e = 0; e < 8; ++e) {
    hi[e] = f2bf_rne(a[e]);
    lo[e] = f2bf_rne(a[e] - bf2f(hi[e]));
  }
  size_t base = (size_t)row * DIM + 4 * l;
  *(ushort4*)&Xhi[base]       = make_ushort4(hi[0], hi[1], hi[2], hi[3]);
  *(ushort4*)&Xhi[base + 256] = make_ushort4(hi[4], hi[5], hi[6], hi[7]);
  *(ushort4*)&Xlo[base]       = make_ushort4(lo[0], lo[1], lo[2], lo[3]);
  *(ushort4*)&Xlo[base + 256] = make_ushort4(lo[4], lo[5], lo[6], lo[7]);
}

__global__ void label_init_kernel(const float* __restrict__ oh, int* __restrict__ lab,
                                  unsigned long long* __restrict__ packed) {
  int i = blockIdx.x * 256 + threadIdx.x;
  if (i < NQ) packed[i] = 0ull;
  if (i < NS) {
    const float* row = oh + (size_t)i * NC;
    int l = 0;
    #pragma unroll
    for (int j = 0; j < NC; ++j) l = (row[j] > 0.5f) ? j : l;
    lab[i] = l;
  }
}

// ---------- main: 256x256 phase-interleaved bf16x3 MFMA + fused argmax ----------
__global__ __launch_bounds__(512, 2) void knn_mfma_kernel(
    const ushort* __restrict__ Qhi, const ushort* __restrict__ Qlo,
    const ushort* __restrict__ Shi, const ushort* __restrict__ Slo,
    unsigned long long* __restrict__ packed)
{
  // [dbuf][mat: Ahi,Alo,Bhi,Blo][256 rows x 32 k] bf16, 64B rows. 128 KB.
  __shared__ ushort tiles[2][4][BM * BK];
  __shared__ unsigned long long merged[BM * 4];   // 8 KB cross-wave argmax merge

  const int tid = threadIdx.x;
  const int w = tid >> 6, l = tid & 63;
  const int wr = w >> 2, wcn = w & 3;       // 2 (M) x 4 (N) wave grid
  const int c = l & 15, g = l >> 4;
  // T2 swizzle: 16B slot s' = s ^ ((row ^ row>>2) & 3); for frag reads row%16==c
  const int sA = ((g ^ (c & 3) ^ ((c >> 2) & 3))) * 8;   // ushort offset of slot

  // T1: XCD-aware block swizzle (512 % 8 == 0, bijective). Each XCD owns 2 s-chunks.
  const int flat = blockIdx.x;
  const int nf = (flat & 7) * 64 + (flat >> 3);
  const int sbq = nf >> 5;                  // 0..15
  const int qb  = nf & 31;                  // 0..31
  const int qbase = qb * BM;
  const int sbase = sbq * SCHUNK;

  // staging geometry: slotid -> (row, slot); source pre-swizzled, LDS dest linear
  const int slot0 = tid, slot1 = tid + 512;
  const int row0 = slot0 >> 2, row1 = slot1 >> 2;
  const int sd0 = ((slot0 & 3) ^ ((row0 ^ (row0 >> 2)) & 3)) * 8;
  const int sd1 = ((slot1 & 3) ^ ((row1 ^ (row1 >> 2)) & 3)) * 8;
  const ushort* qh0 = Qhi + (size_t)(qbase + row0) * DIM + sd0;
  const ushort* qh1 = Qhi + (size_t)(qbase + row1) * DIM + sd1;
  const ushort* ql0 = Qlo + (size_t)(qbase + row0) * DIM + sd0;
  const ushort* ql1 = Qlo + (size_t)(qbase + row1) * DIM + sd1;
  const ushort* sh0 = Shi + (size_t)(sbase + row0) * DIM + sd0;
  const ushort* sh1 = Shi + (size_t)(sbase + row1) * DIM + sd1;
  const ushort* sl0 = Slo + (size_t)(sbase + row0) * DIM + sd0;
  const ushort* sl1 = Slo + (size_t)(sbase + row1) * DIM + sd1;
  const int ld0 = (w * 64) * 8;             // wave-uniform LDS dest (ushort idx)
  const int ld1 = (512 + w * 64) * 8;

  #define STAGE_A(nxt, kk) do {                              \
    gload_lds16(qh0 + (kk), &tiles[(nxt)][0][ld0]);          \
    gload_lds16(qh1 + (kk), &tiles[(nxt)][0][ld1]);          \
    gload_lds16(ql0 + (kk), &tiles[(nxt)][1][ld0]);          \
    gload_lds16(ql1 + (kk), &tiles[(nxt)][1][ld1]);          \
  } while (0)
  #define STAGE_B(nxt, off) do {                             \
    gload_lds16(sh0 + (off), &tiles[(nxt)][2][ld0]);         \
    gload_lds16(sh1 + (off), &tiles[(nxt)][2][ld1]);         \
    gload_lds16(sl0 + (off), &tiles[(nxt)][3][ld0]);         \
    gload_lds16(sl1 + (off), &tiles[(nxt)][3][ld1]);         \
  } while (0)

  f32x4 acc[8][4];
  #pragma unroll
  for (int m = 0; m < 8; ++m)
    #pragma unroll
    for (int n = 0; n < 4; ++n) acc[m][n] = (f32x4)0.0f;
  unsigned long long best2 = 0ull;   // per-thread (tid<256): winner for row qbase+tid

  // prologue: stage K-step 0 into buf 0
  STAGE_A(0, 0);
  STAGE_B(0, 0);
  asm volatile("s_waitcnt vmcnt(0)" ::: "memory");
  __builtin_amdgcn_s_barrier();

  for (int t = 0; t < NTILES; ++t) {
    for (int k16 = 0; k16 < KSTEPS; ++k16) {
      const int ks = t * KSTEPS + k16;
      const int cur = ks & 1, nxt = cur ^ 1;
      const int ks1 = ks + 1;
      const bool pf = (ks1 < TOTKS);
      const int kk1 = (ks1 & (KSTEPS - 1)) * BK;
      const int bo1 = (ks1 >> 4) * BN * DIM + kk1;

      const ushort* Ah = tiles[cur][0];
      const ushort* Al = tiles[cur][1];
      const ushort* Bh = tiles[cur][2];
      const ushort* Bl = tiles[cur][3];
      const int ab = (wr * 128 + c) * BK + sA;
      const int bb = (wcn * 64 + c) * BK + sA;

      bf16x8 ah[8], al[8], bh[4], bl[4];

      // ---- P1: read ah,bh; prefetch A(t+1); MFMA hh ----
      #pragma unroll
      for (int m = 0; m < 8; ++m) ah[m] = *(const bf16x8*)&Ah[ab + m * 16 * BK];
      #pragma unroll
      for (int n = 0; n < 4; ++n) bh[n] = *(const bf16x8*)&Bh[bb + n * 16 * BK];
      if (pf) STAGE_A(nxt, kk1);
      __builtin_amdgcn_s_barrier();
      asm volatile("s_waitcnt lgkmcnt(0)" ::: "memory");
      __builtin_amdgcn_s_setprio(1);
      #pragma unroll
      for (int m = 0; m < 8; ++m)
        #pragma unroll
        for (int n = 0; n < 4; ++n)
          acc[m][n] = __builtin_amdgcn_mfma_f32_16x16x32_bf16(ah[m], bh[n], acc[m][n], 0, 0, 0);
      __builtin_amdgcn_s_setprio(0);
      __builtin_amdgcn_s_barrier();

      // ---- P2: read bl; prefetch B(t+1); MFMA hl ----
      #pragma unroll
      for (int n = 0; n < 4; ++n) bl[n] = *(const bf16x8*)&Bl[bb + n * 16 * BK];
      if (pf) STAGE_B(nxt, bo1);
      __builtin_amdgcn_s_barrier();
      asm volatile("s_waitcnt lgkmcnt(0)" ::: "memory");
      __builtin_amdgcn_s_setprio(1);
      #pragma unroll
      for (int m = 0; m < 8; ++m)
        #pragma unroll
        for (int n = 0; n < 4; ++n)
          acc[m][n] = __builtin_amdgcn_mfma_f32_16x16x32_bf16(ah[m], bl[n], acc[m][n], 0, 0, 0);
      __builtin_amdgcn_s_setprio(0);
      __builtin_amdgcn_s_barrier();

      // ---- P3: read al; MFMA lh; K-step boundary drain ----
      #pragma unroll
      for (int m = 0; m < 8; ++m) al[m] = *(const bf16x8*)&Al[ab + m * 16 * BK];
      __builtin_amdgcn_s_barrier();
      asm volatile("s_waitcnt lgkmcnt(0)" ::: "memory");
      __builtin_amdgcn_s_setprio(1);
      #pragma unroll
      for (int m = 0; m < 8; ++m)
        #pragma unroll
        for (int n = 0; n < 4; ++n)
          acc[m][n] = __builtin_amdgcn_mfma_f32_16x16x32_bf16(al[m], bh[n], acc[m][n], 0, 0, 0);
      __builtin_amdgcn_s_setprio(0);
      asm volatile("s_waitcnt vmcnt(0)" ::: "memory");   // own prefetch landed
      __builtin_amdgcn_s_barrier();                       // all waves' writes visible
    }

    // ---- per-s-tile argmax epilogue (registers + shfl + LDS merge) ----
    {
      const int sb0 = sbase + t * BN + wcn * 64 + c;
      #pragma unroll
      for (int m = 0; m < 8; ++m)
        #pragma unroll
        for (int r = 0; r < 4; ++r) {
          float v = acc[m][0][r];
          int   n = sb0;
          #pragma unroll
          for (int j = 1; j < 4; ++j) {
            float vj = acc[m][j][r];
            int   nj = sb0 + j * 16;
            if (vj > v) { v = vj; n = nj; }   // strict >: keeps lowest index
          }
          #pragma unroll
          for (int off = 1; off < 16; off <<= 1) {
            float ov = __shfl_xor(v, off);
            int   on = __shfl_xor(n, off);
            if (ov > v || (ov == v && on < n)) { v = ov; n = on; }
          }
          if (c == 0) {
            int row = wr * 128 + m * 16 + g * 4 + r;
            merged[row * 4 + wcn] =
                ((unsigned long long)fkey(v) << 32) | (uint32_t)(~(uint32_t)n);
          }
        }
      __syncthreads();
      if (tid < BM) {
        unsigned long long b = merged[tid * 4 + 0];
        #pragma unroll
        for (int j = 1; j < 4; ++j) {
          unsigned long long mj = merged[tid * 4 + j];
          if (mj > b) b = mj;
        }
        if (b > best2) best2 = b;
      }
      #pragma unroll
      for (int m = 0; m < 8; ++m)
        #pragma unroll
        for (int n = 0; n < 4; ++n) acc[m][n] = (f32x4)0.0f;
      // next block-wide barrier (first P1 barrier of next tile, or kernel end)
      // orders these reads before the next merged[] writes
    }
  }

  if (tid < BM) atomicMax(&packed[qbase + tid], best2);

  #undef STAGE_A
  #undef STAGE_B
}

__global__ void finalize_kernel(const unsigned long long* __restrict__ packed,
                                const int* __restrict__ lab, float* __restrict__ out) {
  int gid = blockIdx.x * 256 + threadIdx.x;
  if (gid >= NQ * NC) return;
  int q = gid >> 6;
  int cl = gid & 63;
  unsigned long long p = packed[q];
  uint32_t n = ~(uint32_t)p;
  uint32_t key = (uint32_t)(p >> 32);
  uint32_t u = (key & 0x80000000u) ? (key & 0x7FFFFFFFu) : ~key;
  float v = __uint_as_float(u);
  out[gid] = (cl == lab[n]) ? v : 0.0f;
}

// ---------- launch ----------
extern "C" void kernel_launch(void* const* d_in, const int* in_sizes, int n_in,
                              void* d_out, int out_size, void* d_ws, size_t ws_size,
                              hipStream_t stream) {
  const float* Q  = (const float*)d_in[0];   // [8192, 512]
  const float* S  = (const float*)d_in[1];   // [16384, 512]
  const float* OH = (const float*)d_in[2];   // [16384, 64]
  float* out = (float*)d_out;                // [8192, 64]

  char* ws = (char*)d_ws;
  int* lab = (int*)ws;                                              // 64 KB @ 0
  unsigned long long* packed = (unsigned long long*)(ws + 65536);   // 64 KB

  const size_t QHI = 131072;
  const size_t QLO = QHI + (size_t)NQ * DIM * 2;
  const size_t SHI = QLO + (size_t)NQ * DIM * 2;
  const size_t SLO = SHI + (size_t)NS * DIM * 2;

  ushort* Qhi = (ushort*)(ws + QHI);
  ushort* Qlo = (ushort*)(ws + QLO);
  ushort* Shi = (ushort*)(ws + SHI);
  ushort* Slo = (ushort*)(ws + SLO);

  norm_split_kernel<<<NQ / 4, 256, 0, stream>>>(Q, Qhi, Qlo, NQ);
  norm_split_kernel<<<NS / 4, 256, 0, stream>>>(S, Shi, Slo, NS);
  label_init_kernel<<<NS / 256, 256, 0, stream>>>(OH, lab, packed);

  knn_mfma_kernel<<<(NQ / BM) * SSPLIT, 512, 0, stream>>>(Qhi, Qlo, Shi, Slo, packed);

  finalize_kernel<<<(NQ * NC) / 256, 256, 0, stream>>>(packed, lab, out);
}